// Round 1
// baseline (279.941 us; speedup 1.0000x reference)
//
#include <hip/hip_runtime.h>
#include <hip/hip_bf16.h>

#define C_IN   256
#define C_OUT  512
#define NFILT  4

#define BM 128
#define BN 128
#define BK 32
#define SAS 40   // LDS row stride in bf16 elems: 80 B, keeps 16B alignment, 2-way max bank alias

typedef __attribute__((ext_vector_type(8))) short bf16x8;
typedef __attribute__((ext_vector_type(4))) float floatx4;

union Pack8 { uint4 u; __hip_bfloat16 h[8]; };

__global__ void bucketize_kernel(const float* __restrict__ xyz,
                                 int* __restrict__ idxbuf,
                                 int* __restrict__ cnt, int P) {
    int pid = blockIdx.x * blockDim.x + threadIdx.x;
    if (pid >= P) return;
    float x = xyz[pid * 3 + 0];
    float y = xyz[pid * 3 + 1];
    float z = xyz[pid * 3 + 2];
    // match np: non-fused fp32 sum of squares, then sqrt, then strict <
    float r2 = __fadd_rn(__fadd_rn(__fmul_rn(x, x), __fmul_rn(y, y)), __fmul_rn(z, z));
    float r = sqrtf(r2);
    int filt;
    if (r < 1.0f)        filt = 0;
    else if (r < 1.5f)   filt = 1;
    else if (r < 2.0f)   filt = 2;
    else if (r < 100.0f) filt = 3;
    else                 filt = 0;   // argmax over all-false booleans returns 0

    int lane = threadIdx.x & 63;
    for (int f = 0; f < NFILT; ++f) {
        unsigned long long mask = __ballot(filt == f);
        if (mask == 0ull) continue;
        int leader = __ffsll((unsigned long long)mask) - 1;
        int base = 0;
        if (lane == leader) base = atomicAdd(&cnt[f], __popcll(mask));
        base = __shfl(base, leader);
        if (filt == f) {
            int off = __popcll(mask & ((1ull << lane) - 1ull));
            idxbuf[f * P + base + off] = pid;
        }
    }
}

// also zeroes cnt (runs before bucketize on the same stream)
__global__ void convert_w_kernel(const float* __restrict__ w,
                                 ushort* __restrict__ wb,
                                 int* __restrict__ cnt) {
    if (blockIdx.x == 0 && threadIdx.x < NFILT) cnt[threadIdx.x] = 0;
    int i = (blockIdx.x * blockDim.x + threadIdx.x) * 4;
    float4 v = *(const float4*)(w + i);
    union { ushort4 u; __hip_bfloat16 h[4]; } cv;
    cv.h[0] = __float2bfloat16(v.x);
    cv.h[1] = __float2bfloat16(v.y);
    cv.h[2] = __float2bfloat16(v.z);
    cv.h[3] = __float2bfloat16(v.w);
    *(ushort4*)(wb + i) = cv.u;
}

__global__ __launch_bounds__(256) void gemm_kernel(
    const float* __restrict__ feat, const ushort* __restrict__ wb,
    const float* __restrict__ bias, const int* __restrict__ idxbuf,
    const int* __restrict__ cnt, float* __restrict__ out, int P)
{
    __shared__ ushort sA[BM * SAS];
    __shared__ ushort sB[BN * SAS];
    __shared__ int    sIdx[BM];
    __shared__ float  sBias[BN];

    // ---- XCD-aware swizzle: the 4 col-tiles of one row-tile become 4
    // consecutive blocks in one XCD's round-robin stream (lid % 8 == XCD),
    // so the gathered A tile is fetched into that XCD's L2 once.
    // gridDim.x == 4 (C_OUT/BN); gridDim.y padded to a multiple of 8.
    int lid = blockIdx.x + (blockIdx.y << 2);
    int g = lid & 7;
    int q = lid >> 3;
    int cTile = q & 3;                 // col tile 0..3
    int t = ((q >> 2) << 3) + g;       // row tile id (bijective, padded range)

    int counts[4];
    counts[0] = cnt[0]; counts[1] = cnt[1]; counts[2] = cnt[2]; counts[3] = cnt[3];
    int f = -1, lt = 0;
    for (int ff = 0; ff < 4; ++ff) {
        int nt = (counts[ff] + BM - 1) / BM;
        if (t < nt) { f = ff; lt = t; break; }
        t -= nt;
    }
    if (f < 0) return;

    int tid = threadIdx.x;
    int oBase = cTile * BN;
    int rowBase = lt * BM;
    int cn = counts[f];

    if (tid < BM) {
        int r = rowBase + tid;
        sIdx[tid] = (r < cn) ? idxbuf[f * P + r] : -1;
    }
    if (tid < BN) sBias[tid] = bias[f * C_OUT + oBase + tid];
    __syncthreads();

    // ---- staging assignment: thread covers 16 elems of one row per K-step ----
    int sRow = tid >> 1;       // 0..127
    int sHalf = tid & 1;       // 0..1
    int myIdx = sIdx[sRow];
    const float* aRow = feat + (size_t)(myIdx < 0 ? 0 : myIdx) * C_IN + sHalf * 16;
    const ushort* bRow = wb + (size_t)(f * C_OUT + oBase + sRow) * C_IN + sHalf * 16;

    int wid = tid >> 6;
    int lane = tid & 63;
    int wm = (wid >> 1) * 64;
    int wn = (wid & 1) * 64;
    int lcol = lane & 15;
    int quad = lane >> 4;

    floatx4 acc[4][4];
#pragma unroll
    for (int i = 0; i < 4; ++i)
#pragma unroll
        for (int j = 0; j < 4; ++j)
            acc[i][j] = (floatx4){0.f, 0.f, 0.f, 0.f};

    ushort* dA = &sA[sRow * SAS + sHalf * 16];
    ushort* dB = &sB[sRow * SAS + sHalf * 16];

    // ---- prologue: issue K-step 0 loads ----
    float4 a0 = *(const float4*)(aRow + 0);
    float4 a1 = *(const float4*)(aRow + 4);
    float4 a2 = *(const float4*)(aRow + 8);
    float4 a3 = *(const float4*)(aRow + 12);
    uint4  b01 = *(const uint4*)(bRow + 0);
    uint4  b23 = *(const uint4*)(bRow + 8);

    // ---- pipelined K-loop: next step's global loads stay in flight across
    // raw s_barriers (only lgkmcnt drained — no vmcnt(0) drain as with
    // __syncthreads), overlapping HBM gather latency with convert+MFMA.
#pragma unroll
    for (int s = 0; s < 8; ++s) {
        float4 n0, n1, n2, n3;
        uint4  nb01, nb23;
        if (s < 7) {                       // issue prefetch for step s+1 first
            const float*  ap = aRow + (s + 1) * BK;
            const ushort* bp = bRow + (s + 1) * BK;
            n0   = *(const float4*)(ap + 0);
            n1   = *(const float4*)(ap + 4);
            n2   = *(const float4*)(ap + 8);
            n3   = *(const float4*)(ap + 12);
            nb01 = *(const uint4*)(bp + 0);
            nb23 = *(const uint4*)(bp + 8);
        }

        // convert current A -> bf16, pack, stage A+B to LDS
        Pack8 p0, p1;
        p0.h[0] = __float2bfloat16(a0.x); p0.h[1] = __float2bfloat16(a0.y);
        p0.h[2] = __float2bfloat16(a0.z); p0.h[3] = __float2bfloat16(a0.w);
        p0.h[4] = __float2bfloat16(a1.x); p0.h[5] = __float2bfloat16(a1.y);
        p0.h[6] = __float2bfloat16(a1.z); p0.h[7] = __float2bfloat16(a1.w);
        p1.h[0] = __float2bfloat16(a2.x); p1.h[1] = __float2bfloat16(a2.y);
        p1.h[2] = __float2bfloat16(a2.z); p1.h[3] = __float2bfloat16(a2.w);
        p1.h[4] = __float2bfloat16(a3.x); p1.h[5] = __float2bfloat16(a3.y);
        p1.h[6] = __float2bfloat16(a3.z); p1.h[7] = __float2bfloat16(a3.w);
        *(uint4*)(dA + 0) = p0.u;
        *(uint4*)(dA + 8) = p1.u;
        *(uint4*)(dB + 0) = b01;
        *(uint4*)(dB + 8) = b23;

        // LDS-only barrier: all waves' ds_writes visible, vmcnt NOT drained
        asm volatile("s_waitcnt lgkmcnt(0)" ::: "memory");
        __builtin_amdgcn_s_barrier();
        __builtin_amdgcn_sched_barrier(0);

        bf16x8 af[4], bfr[4];
#pragma unroll
        for (int i = 0; i < 4; ++i)
            af[i] = *(const bf16x8*)&sA[(wm + i * 16 + lcol) * SAS + quad * 8];
#pragma unroll
        for (int j = 0; j < 4; ++j)
            bfr[j] = *(const bf16x8*)&sB[(wn + j * 16 + lcol) * SAS + quad * 8];
#pragma unroll
        for (int i = 0; i < 4; ++i)
#pragma unroll
            for (int j = 0; j < 4; ++j)
                acc[i][j] = __builtin_amdgcn_mfma_f32_16x16x32_bf16(af[i], bfr[j], acc[i][j], 0, 0, 0);

        // LDS-only barrier before next step's ds_writes overwrite the buffer
        asm volatile("s_waitcnt lgkmcnt(0)" ::: "memory");
        __builtin_amdgcn_s_barrier();
        __builtin_amdgcn_sched_barrier(0);

        if (s < 7) {
            a0 = n0; a1 = n1; a2 = n2; a3 = n3;
            b01 = nb01; b23 = nb23;
        }
    }

    // ---- epilogue: scatter rows by original point id, add bias ----
#pragma unroll
    for (int i = 0; i < 4; ++i) {
        int r0 = wm + i * 16 + quad * 4;
        int pid0 = sIdx[r0 + 0];
        int pid1 = sIdx[r0 + 1];
        int pid2 = sIdx[r0 + 2];
        int pid3 = sIdx[r0 + 3];
#pragma unroll
        for (int j = 0; j < 4; ++j) {
            int o = oBase + wn + j * 16 + lcol;
            float bv = sBias[wn + j * 16 + lcol];
            if (pid0 >= 0) out[pid0 * C_OUT + o] = acc[i][j][0] + bv;
            if (pid1 >= 0) out[pid1 * C_OUT + o] = acc[i][j][1] + bv;
            if (pid2 >= 0) out[pid2 * C_OUT + o] = acc[i][j][2] + bv;
            if (pid3 >= 0) out[pid3 * C_OUT + o] = acc[i][j][3] + bv;
        }
    }
}

extern "C" void kernel_launch(void* const* d_in, const int* in_sizes, int n_in,
                              void* d_out, int out_size, void* d_ws, size_t ws_size,
                              hipStream_t stream) {
    const float* feat = (const float*)d_in[0];
    const float* xyz  = (const float*)d_in[1];
    const float* w    = (const float*)d_in[2];
    const float* bias = (const float*)d_in[3];
    float* out = (float*)d_out;
    int P = in_sizes[0] / C_IN;

    char* ws = (char*)d_ws;
    int* idxbuf = (int*)ws;                                    // 4*P ints
    int* cntp   = (int*)(ws + (size_t)4 * P * 4);              // 4 ints
    ushort* wb  = (ushort*)(ws + (size_t)4 * P * 4 + 16);      // NFILT*C_OUT*C_IN bf16

    // convert_w also zeroes cnt; stream order guarantees visibility to bucketize
    convert_w_kernel<<<(NFILT * C_OUT * C_IN) / 1024, 256, 0, stream>>>(w, wb, cntp);
    bucketize_kernel<<<(P + 255) / 256, 256, 0, stream>>>(xyz, idxbuf, cntp, P);

    // grid.y padded to a multiple of 8 row-tiles so the XCD swizzle is bijective;
    // out-of-range tiles early-return via the f<0 path.
    int tilesY = ((P / BM + NFILT + 7) / 8) * 8;
    dim3 grid(C_OUT / BN, tilesY);
    gemm_kernel<<<grid, 256, 0, stream>>>(feat, wb, bias, idxbuf, cntp, out, P);
}

// Round 2
// 278.362 us; speedup vs baseline: 1.0057x; 1.0057x over previous
//
#include <hip/hip_runtime.h>
#include <hip/hip_bf16.h>

#define C_IN   256
#define C_OUT  512
#define NFILT  4

#define BM 128
#define BN 128
#define BK 32
#define SAS 40   // old-path LDS row stride

// fast path geometry
#define FBK 64   // bf16 elems per K-step; C_IN/FBK = 4 steps

typedef __attribute__((ext_vector_type(8))) short bf16x8;
typedef __attribute__((ext_vector_type(4))) float floatx4;

union Pack8 { uint4 u; __hip_bfloat16 h[8]; };

__global__ void bucketize_kernel(const float* __restrict__ xyz,
                                 int* __restrict__ idxbuf,
                                 int* __restrict__ cnt, int P) {
    int pid = blockIdx.x * blockDim.x + threadIdx.x;
    if (pid >= P) return;
    float x = xyz[pid * 3 + 0];
    float y = xyz[pid * 3 + 1];
    float z = xyz[pid * 3 + 2];
    // match np: non-fused fp32 sum of squares, then sqrt, then strict <
    float r2 = __fadd_rn(__fadd_rn(__fmul_rn(x, x), __fmul_rn(y, y)), __fmul_rn(z, z));
    float r = sqrtf(r2);
    int filt;
    if (r < 1.0f)        filt = 0;
    else if (r < 1.5f)   filt = 1;
    else if (r < 2.0f)   filt = 2;
    else if (r < 100.0f) filt = 3;
    else                 filt = 0;   // argmax over all-false booleans returns 0

    int lane = threadIdx.x & 63;
    for (int f = 0; f < NFILT; ++f) {
        unsigned long long mask = __ballot(filt == f);
        if (mask == 0ull) continue;
        int leader = __ffsll((unsigned long long)mask) - 1;
        int base = 0;
        if (lane == leader) base = atomicAdd(&cnt[f], __popcll(mask));
        base = __shfl(base, leader);
        if (filt == f) {
            int off = __popcll(mask & ((1ull << lane) - 1ull));
            idxbuf[f * P + base + off] = pid;
        }
    }
}

// also zeroes cnt (runs before bucketize on the same stream)
__global__ void convert_w_kernel(const float* __restrict__ w,
                                 ushort* __restrict__ wb,
                                 int* __restrict__ cnt) {
    if (blockIdx.x == 0 && threadIdx.x < NFILT) cnt[threadIdx.x] = 0;
    int i = (blockIdx.x * blockDim.x + threadIdx.x) * 4;
    float4 v = *(const float4*)(w + i);
    union { ushort4 u; __hip_bfloat16 h[4]; } cv;
    cv.h[0] = __float2bfloat16(v.x);
    cv.h[1] = __float2bfloat16(v.y);
    cv.h[2] = __float2bfloat16(v.z);
    cv.h[3] = __float2bfloat16(v.w);
    *(ushort4*)(wb + i) = cv.u;
}

// gather feat rows into bucket-contiguous order, fp32 -> bf16, once.
// one wave per output row (256 floats = 64 lanes x float4).
__global__ __launch_bounds__(256) void gather_kernel(
    const float* __restrict__ feat, const int* __restrict__ idxbuf,
    const int* __restrict__ cnt, ushort* __restrict__ gA, int P)
{
    int wid = threadIdx.x >> 6;
    int lane = threadIdx.x & 63;
    int slot = blockIdx.x * 4 + wid;
    if (slot >= P) return;
    int c0 = cnt[0], c1 = cnt[1], c2 = cnt[2];
    int b1 = c0, b2 = c0 + c1, b3 = c0 + c1 + c2;
    int f, i;
    if (slot < b1)      { f = 0; i = slot; }
    else if (slot < b2) { f = 1; i = slot - b1; }
    else if (slot < b3) { f = 2; i = slot - b2; }
    else                { f = 3; i = slot - b3; }
    int pid = idxbuf[f * P + i];
    float4 v = *(const float4*)(feat + (size_t)pid * C_IN + lane * 4);
    union { ushort4 u; __hip_bfloat16 h[4]; } cv;
    cv.h[0] = __float2bfloat16(v.x);
    cv.h[1] = __float2bfloat16(v.y);
    cv.h[2] = __float2bfloat16(v.z);
    cv.h[3] = __float2bfloat16(v.w);
    *(ushort4*)(gA + (size_t)slot * C_IN + lane * 4) = cv.u;
}

// dense bf16 GEMM over the gathered buffer (m97 structure: global_load_lds
// width-16 staging, single-buffered LDS, 2 barriers per K-step, BK=64).
__global__ __launch_bounds__(256) void gemm_fast_kernel(
    const ushort* __restrict__ gA, const ushort* __restrict__ wb,
    const float* __restrict__ bias, const int* __restrict__ idxbuf,
    const int* __restrict__ cnt, float* __restrict__ out, int P)
{
    __shared__ ushort sA[BM * FBK];   // 16 KB, linear (gload_lds dest)
    __shared__ ushort sB[BN * FBK];   // 16 KB
    __shared__ int    sIdx[BM];
    __shared__ float  sBias[BN];

    // XCD-aware swizzle: 4 col-tiles of one row-tile land consecutively in
    // one XCD's round-robin stream. gridDim.x == 4, gridDim.y % 8 == 0.
    int lid = blockIdx.x + (blockIdx.y << 2);
    int g = lid & 7;
    int q = lid >> 3;
    int cTile = q & 3;
    int t = ((q >> 2) << 3) + g;

    int c0 = cnt[0], c1 = cnt[1], c2 = cnt[2], c3 = cnt[3];
    int counts[4] = {c0, c1, c2, c3};
    int bases[4]  = {0, c0, c0 + c1, c0 + c1 + c2};
    int f = -1, lt = 0;
    for (int ff = 0; ff < 4; ++ff) {
        int nt = (counts[ff] + BM - 1) / BM;
        if (t < nt) { f = ff; lt = t; break; }
        t -= nt;
    }
    if (f < 0) return;

    int tid = threadIdx.x;
    int oBase = cTile * BN;
    int cn = counts[f];
    int gBase = bases[f] + lt * BM;       // first gathered row of this tile
    int wRow0 = f * C_OUT + oBase;        // first weight row of this tile

    if (tid < BM) {
        int r = lt * BM + tid;
        sIdx[tid] = (r < cn) ? idxbuf[f * P + r] : -1;
    }
    if (tid < BN) sBias[tid] = bias[f * C_OUT + oBase + tid];
    __syncthreads();

    int wid = tid >> 6;
    int lane = tid & 63;
    int wm = (wid >> 1) * 64;
    int wn = (wid & 1) * 64;
    int lcol = lane & 15;
    int quad = lane >> 4;
    int rp = lcol & 7;                    // read-side swizzle parity

    // staging lane geometry: each wave-issue covers 1 KB = 8 rows x 128 B.
    int lrow = lane >> 3;                 // row within the 8-row segment
    int lchunk = lane & 7;                // 16B chunk within the row
    int schunk = lchunk ^ lrow;           // pre-swizzled SOURCE chunk (T2 via m173)

    floatx4 acc[4][4];
#pragma unroll
    for (int i = 0; i < 4; ++i)
#pragma unroll
        for (int j = 0; j < 4; ++j)
            acc[i][j] = (floatx4){0.f, 0.f, 0.f, 0.f};

    const char* aBase = (const char*)gA;
    const char* bBase = (const char*)wb;

#pragma unroll
    for (int s = 0; s < C_IN / FBK; ++s) {
        int kByte = s * (FBK * 2);
#pragma unroll
        for (int n = 0; n < 4; ++n) {
            int seg = wid * 4 + n;        // 0..15, 1 KB each
            int row = seg * 8 + lrow;
            const char* srcA = aBase + ((size_t)(gBase + row) * (C_IN * 2)) + kByte + schunk * 16;
            __builtin_amdgcn_global_load_lds(
                (const __attribute__((address_space(1))) void*)srcA,
                (__attribute__((address_space(3))) void*)&sA[seg * 512], 16, 0, 0);
            const char* srcB = bBase + ((size_t)(wRow0 + row) * (C_IN * 2)) + kByte + schunk * 16;
            __builtin_amdgcn_global_load_lds(
                (const __attribute__((address_space(1))) void*)srcB,
                (__attribute__((address_space(3))) void*)&sB[seg * 512], 16, 0, 0);
        }
        asm volatile("s_waitcnt vmcnt(0)" ::: "memory");
        __builtin_amdgcn_s_barrier();
        __builtin_amdgcn_sched_barrier(0);

#pragma unroll
        for (int kk2 = 0; kk2 < 2; ++kk2) {
            int ck = ((kk2 * 4 + quad) ^ rp) * 8;   // swizzled 8-elem chunk
            bf16x8 af[4], bfr[4];
#pragma unroll
            for (int i = 0; i < 4; ++i)
                af[i] = *(const bf16x8*)&sA[(wm + i * 16 + lcol) * FBK + ck];
#pragma unroll
            for (int j = 0; j < 4; ++j)
                bfr[j] = *(const bf16x8*)&sB[(wn + j * 16 + lcol) * FBK + ck];
#pragma unroll
            for (int i = 0; i < 4; ++i)
#pragma unroll
                for (int j = 0; j < 4; ++j)
                    acc[i][j] = __builtin_amdgcn_mfma_f32_16x16x32_bf16(af[i], bfr[j], acc[i][j], 0, 0, 0);
        }
        if (s < C_IN / FBK - 1) __syncthreads();
    }

    // epilogue: scatter rows by original point id, add bias
#pragma unroll
    for (int i = 0; i < 4; ++i) {
        int r0 = wm + i * 16 + quad * 4;
        int pid0 = sIdx[r0 + 0];
        int pid1 = sIdx[r0 + 1];
        int pid2 = sIdx[r0 + 2];
        int pid3 = sIdx[r0 + 3];
#pragma unroll
        for (int j = 0; j < 4; ++j) {
            int o = oBase + wn + j * 16 + lcol;
            float bv = sBias[wn + j * 16 + lcol];
            if (pid0 >= 0) out[pid0 * C_OUT + o] = acc[i][j][0] + bv;
            if (pid1 >= 0) out[pid1 * C_OUT + o] = acc[i][j][1] + bv;
            if (pid2 >= 0) out[pid2 * C_OUT + o] = acc[i][j][2] + bv;
            if (pid3 >= 0) out[pid3 * C_OUT + o] = acc[i][j][3] + bv;
        }
    }
}

// ---------------- fallback (old fused) gemm, used only if ws too small ----
__global__ __launch_bounds__(256) void gemm_kernel(
    const float* __restrict__ feat, const ushort* __restrict__ wb,
    const float* __restrict__ bias, const int* __restrict__ idxbuf,
    const int* __restrict__ cnt, float* __restrict__ out, int P)
{
    __shared__ ushort sA[BM * SAS];
    __shared__ ushort sB[BN * SAS];
    __shared__ int    sIdx[BM];
    __shared__ float  sBias[BN];

    int lid = blockIdx.x + (blockIdx.y << 2);
    int g = lid & 7;
    int q = lid >> 3;
    int cTile = q & 3;
    int t = ((q >> 2) << 3) + g;

    int counts[4];
    counts[0] = cnt[0]; counts[1] = cnt[1]; counts[2] = cnt[2]; counts[3] = cnt[3];
    int f = -1, lt = 0;
    for (int ff = 0; ff < 4; ++ff) {
        int nt = (counts[ff] + BM - 1) / BM;
        if (t < nt) { f = ff; lt = t; break; }
        t -= nt;
    }
    if (f < 0) return;

    int tid = threadIdx.x;
    int oBase = cTile * BN;
    int rowBase = lt * BM;
    int cn = counts[f];

    if (tid < BM) {
        int r = rowBase + tid;
        sIdx[tid] = (r < cn) ? idxbuf[f * P + r] : -1;
    }
    if (tid < BN) sBias[tid] = bias[f * C_OUT + oBase + tid];
    __syncthreads();

    int sRow = tid >> 1;
    int sHalf = tid & 1;
    int myIdx = sIdx[sRow];
    const float* aRow = feat + (size_t)(myIdx < 0 ? 0 : myIdx) * C_IN + sHalf * 16;
    const ushort* bRow = wb + (size_t)(f * C_OUT + oBase + sRow) * C_IN + sHalf * 16;

    int wid = tid >> 6;
    int lane = tid & 63;
    int wm = (wid >> 1) * 64;
    int wn = (wid & 1) * 64;
    int lcol = lane & 15;
    int quad = lane >> 4;

    floatx4 acc[4][4];
#pragma unroll
    for (int i = 0; i < 4; ++i)
#pragma unroll
        for (int j = 0; j < 4; ++j)
            acc[i][j] = (floatx4){0.f, 0.f, 0.f, 0.f};

    for (int kk = 0; kk < C_IN; kk += BK) {
        const float* ap = aRow + kk;
        float4 a0 = *(const float4*)(ap + 0);
        float4 a1 = *(const float4*)(ap + 4);
        float4 a2 = *(const float4*)(ap + 8);
        float4 a3 = *(const float4*)(ap + 12);
        const ushort* bp = bRow + kk;
        uint4 b01 = *(const uint4*)(bp + 0);
        uint4 b23 = *(const uint4*)(bp + 8);

        Pack8 p0, p1;
        p0.h[0] = __float2bfloat16(a0.x); p0.h[1] = __float2bfloat16(a0.y);
        p0.h[2] = __float2bfloat16(a0.z); p0.h[3] = __float2bfloat16(a0.w);
        p0.h[4] = __float2bfloat16(a1.x); p0.h[5] = __float2bfloat16(a1.y);
        p0.h[6] = __float2bfloat16(a1.z); p0.h[7] = __float2bfloat16(a1.w);
        p1.h[0] = __float2bfloat16(a2.x); p1.h[1] = __float2bfloat16(a2.y);
        p1.h[2] = __float2bfloat16(a2.z); p1.h[3] = __float2bfloat16(a2.w);
        p1.h[4] = __float2bfloat16(a3.x); p1.h[5] = __float2bfloat16(a3.y);
        p1.h[6] = __float2bfloat16(a3.z); p1.h[7] = __float2bfloat16(a3.w);

        ushort* dA = &sA[sRow * SAS + sHalf * 16];
        *(uint4*)(dA + 0) = p0.u;
        *(uint4*)(dA + 8) = p1.u;
        ushort* dB = &sB[sRow * SAS + sHalf * 16];
        *(uint4*)(dB + 0) = b01;
        *(uint4*)(dB + 8) = b23;

        __syncthreads();

        bf16x8 af[4], bfr[4];
#pragma unroll
        for (int i = 0; i < 4; ++i)
            af[i] = *(const bf16x8*)&sA[(wm + i * 16 + lcol) * SAS + quad * 8];
#pragma unroll
        for (int j = 0; j < 4; ++j)
            bfr[j] = *(const bf16x8*)&sB[(wn + j * 16 + lcol) * SAS + quad * 8];
#pragma unroll
        for (int i = 0; i < 4; ++i)
#pragma unroll
            for (int j = 0; j < 4; ++j)
                acc[i][j] = __builtin_amdgcn_mfma_f32_16x16x32_bf16(af[i], bfr[j], acc[i][j], 0, 0, 0);

        __syncthreads();
    }

#pragma unroll
    for (int i = 0; i < 4; ++i) {
        int r0 = wm + i * 16 + quad * 4;
        int pid0 = sIdx[r0 + 0];
        int pid1 = sIdx[r0 + 1];
        int pid2 = sIdx[r0 + 2];
        int pid3 = sIdx[r0 + 3];
#pragma unroll
        for (int j = 0; j < 4; ++j) {
            int o = oBase + wn + j * 16 + lcol;
            float bv = sBias[wn + j * 16 + lcol];
            if (pid0 >= 0) out[pid0 * C_OUT + o] = acc[i][j][0] + bv;
            if (pid1 >= 0) out[pid1 * C_OUT + o] = acc[i][j][1] + bv;
            if (pid2 >= 0) out[pid2 * C_OUT + o] = acc[i][j][2] + bv;
            if (pid3 >= 0) out[pid3 * C_OUT + o] = acc[i][j][3] + bv;
        }
    }
}

extern "C" void kernel_launch(void* const* d_in, const int* in_sizes, int n_in,
                              void* d_out, int out_size, void* d_ws, size_t ws_size,
                              hipStream_t stream) {
    const float* feat = (const float*)d_in[0];
    const float* xyz  = (const float*)d_in[1];
    const float* w    = (const float*)d_in[2];
    const float* bias = (const float*)d_in[3];
    float* out = (float*)d_out;
    int P = in_sizes[0] / C_IN;

    char* ws = (char*)d_ws;
    size_t offIdx = 0;
    size_t offCnt = (size_t)4 * P * 4;
    size_t offWb  = offCnt + 16;
    size_t offGA  = (offWb + (size_t)NFILT * C_OUT * C_IN * 2 + 255) & ~(size_t)255;
    size_t needed = offGA + (size_t)(P + BM) * C_IN * 2;   // +BM rows slack for padded tiles

    int* idxbuf = (int*)(ws + offIdx);
    int* cntp   = (int*)(ws + offCnt);
    ushort* wb  = (ushort*)(ws + offWb);

    // convert_w also zeroes cnt; stream order guarantees visibility
    convert_w_kernel<<<(NFILT * C_OUT * C_IN) / 1024, 256, 0, stream>>>(w, wb, cntp);
    bucketize_kernel<<<(P + 255) / 256, 256, 0, stream>>>(xyz, idxbuf, cntp, P);

    int tilesY = ((P / BM + NFILT + 7) / 8) * 8;   // padded so XCD swizzle is bijective
    dim3 grid(C_OUT / BN, tilesY);

    if (ws_size >= needed) {
        ushort* gA = (ushort*)(ws + offGA);
        gather_kernel<<<(P + 3) / 4, 256, 0, stream>>>(feat, idxbuf, cntp, gA, P);
        gemm_fast_kernel<<<grid, 256, 0, stream>>>(gA, wb, bias, idxbuf, cntp, out, P);
    } else {
        gemm_kernel<<<grid, 256, 0, stream>>>(feat, wb, bias, idxbuf, cntp, out, P);
    }
}

// Round 3
// 233.823 us; speedup vs baseline: 1.1972x; 1.1905x over previous
//
#include <hip/hip_runtime.h>
#include <hip/hip_bf16.h>

#define C_IN   256
#define C_OUT  512
#define NFILT  4

#define BM 128
#define BN 128
#define BK 32
#define SAS 40   // old-path LDS row stride

// fast path geometry
#define FBK 64   // bf16 elems per K-step; C_IN/FBK = 4 steps

typedef __attribute__((ext_vector_type(8))) short bf16x8;
typedef __attribute__((ext_vector_type(4))) float floatx4;

union Pack8 { uint4 u; __hip_bfloat16 h[8]; };

// ---- bucketize: per-block LDS histogram, 4 global atomics per block ----
// 1024-thread blocks -> 64 blocks at P=65536 -> 256 same-line global atomics
// total (vs 4096 in the per-wave version; that line ping-ponged across XCDs).
__global__ __launch_bounds__(1024) void bucketize_kernel(
    const float* __restrict__ xyz, int* __restrict__ idxbuf,
    int* __restrict__ cnt, int P)
{
    __shared__ int hist[NFILT];        // block totals
    __shared__ int wbase[16][NFILT];   // per-wave base within block
    __shared__ int gbase[NFILT];       // block's global base per filter

    int tid = threadIdx.x;
    int wid = tid >> 6;
    int lane = tid & 63;
    if (tid < NFILT) hist[tid] = 0;
    __syncthreads();

    int pid = blockIdx.x * 1024 + tid;
    int filt = -1;
    if (pid < P) {
        float x = xyz[pid * 3 + 0];
        float y = xyz[pid * 3 + 1];
        float z = xyz[pid * 3 + 2];
        // match np: non-fused fp32 sum of squares, then sqrt, then strict <
        float r2 = __fadd_rn(__fadd_rn(__fmul_rn(x, x), __fmul_rn(y, y)), __fmul_rn(z, z));
        float r = sqrtf(r2);
        if (r < 1.0f)        filt = 0;
        else if (r < 1.5f)   filt = 1;
        else if (r < 2.0f)   filt = 2;
        else if (r < 100.0f) filt = 3;
        else                 filt = 0;   // argmax over all-false booleans returns 0
    }

    int myoff = 0;
#pragma unroll
    for (int f = 0; f < NFILT; ++f) {
        unsigned long long m = __ballot(filt == f);
        if (lane == 0) wbase[wid][f] = atomicAdd(&hist[f], (int)__popcll(m));
        if (filt == f) myoff = __popcll(m & ((1ull << lane) - 1ull));
    }
    __syncthreads();
    if (tid < NFILT) gbase[tid] = atomicAdd(&cnt[tid], hist[tid]);
    __syncthreads();

    if (filt >= 0)
        idxbuf[filt * P + gbase[filt] + wbase[wid][filt] + myoff] = pid;
}

// also zeroes cnt (runs before bucketize on the same stream)
__global__ void convert_w_kernel(const float* __restrict__ w,
                                 ushort* __restrict__ wb,
                                 int* __restrict__ cnt) {
    if (blockIdx.x == 0 && threadIdx.x < NFILT) cnt[threadIdx.x] = 0;
    int i = (blockIdx.x * blockDim.x + threadIdx.x) * 4;
    float4 v = *(const float4*)(w + i);
    union { ushort4 u; __hip_bfloat16 h[4]; } cv;
    cv.h[0] = __float2bfloat16(v.x);
    cv.h[1] = __float2bfloat16(v.y);
    cv.h[2] = __float2bfloat16(v.z);
    cv.h[3] = __float2bfloat16(v.w);
    *(ushort4*)(wb + i) = cv.u;
}

// gather feat rows into bucket-contiguous order, fp32 -> bf16, once.
// one wave per output row (256 floats = 64 lanes x float4).
__global__ __launch_bounds__(256) void gather_kernel(
    const float* __restrict__ feat, const int* __restrict__ idxbuf,
    const int* __restrict__ cnt, ushort* __restrict__ gA, int P)
{
    int wid = threadIdx.x >> 6;
    int lane = threadIdx.x & 63;
    int slot = blockIdx.x * 4 + wid;
    if (slot >= P) return;
    int c0 = cnt[0], c1 = cnt[1], c2 = cnt[2];
    int b1 = c0, b2 = c0 + c1, b3 = c0 + c1 + c2;
    int f, i;
    if (slot < b1)      { f = 0; i = slot; }
    else if (slot < b2) { f = 1; i = slot - b1; }
    else if (slot < b3) { f = 2; i = slot - b2; }
    else                { f = 3; i = slot - b3; }
    int pid = idxbuf[f * P + i];
    float4 v = *(const float4*)(feat + (size_t)pid * C_IN + lane * 4);
    union { ushort4 u; __hip_bfloat16 h[4]; } cv;
    cv.h[0] = __float2bfloat16(v.x);
    cv.h[1] = __float2bfloat16(v.y);
    cv.h[2] = __float2bfloat16(v.z);
    cv.h[3] = __float2bfloat16(v.w);
    *(ushort4*)(gA + (size_t)slot * C_IN + lane * 4) = cv.u;
}

// stage K-step s of A and B tiles into LDS buffer b via global_load_lds w=16
#define STAGE(s, b) do {                                                        \
    int kByte = (s) * (FBK * 2);                                                \
    _Pragma("unroll")                                                           \
    for (int n = 0; n < 4; ++n) {                                               \
        int seg = wid * 4 + n;                                                  \
        int row = seg * 8 + lrow;                                               \
        const char* srcA = aBase + ((size_t)(gBase + row) * (C_IN * 2))         \
                                 + kByte + schunk * 16;                         \
        __builtin_amdgcn_global_load_lds(                                       \
            (const __attribute__((address_space(1))) void*)srcA,                \
            (__attribute__((address_space(3))) void*)&sA[b][seg * 512], 16, 0, 0); \
        const char* srcB = bBase + ((size_t)(wRow0 + row) * (C_IN * 2))         \
                                 + kByte + schunk * 16;                         \
        __builtin_amdgcn_global_load_lds(                                       \
            (const __attribute__((address_space(1))) void*)srcB,                \
            (__attribute__((address_space(3))) void*)&sB[b][seg * 512], 16, 0, 0); \
    }                                                                           \
} while (0)

// dense bf16 GEMM over the gathered buffer: 2-phase double-buffered pipeline
// (T3-minimum): STAGE(t+1) issued before compute(t), one vmcnt(0)+barrier per
// K-step so the stage latency overlaps ds_read+MFMA of the current step.
__global__ __launch_bounds__(256) void gemm_fast_kernel(
    const ushort* __restrict__ gA, const ushort* __restrict__ wb,
    const float* __restrict__ bias, const int* __restrict__ idxbuf,
    const int* __restrict__ cnt, float* __restrict__ out, int P)
{
    __shared__ ushort sA[2][BM * FBK];   // 2 x 16 KB, linear (gload_lds dest)
    __shared__ ushort sB[2][BN * FBK];   // 2 x 16 KB
    __shared__ int    sIdx[BM];
    __shared__ float  sBias[BN];

    // XCD-aware swizzle: 4 col-tiles of one row-tile land consecutively in
    // one XCD's round-robin stream. gridDim.x == 4, gridDim.y % 8 == 0.
    int lid = blockIdx.x + (blockIdx.y << 2);
    int g = lid & 7;
    int q = lid >> 3;
    int cTile = q & 3;
    int t = ((q >> 2) << 3) + g;

    int c0 = cnt[0], c1 = cnt[1], c2 = cnt[2], c3 = cnt[3];
    int counts[4] = {c0, c1, c2, c3};
    int bases[4]  = {0, c0, c0 + c1, c0 + c1 + c2};
    int f = -1, lt = 0;
    for (int ff = 0; ff < 4; ++ff) {
        int nt = (counts[ff] + BM - 1) / BM;
        if (t < nt) { f = ff; lt = t; break; }
        t -= nt;
    }
    if (f < 0) return;

    int tid = threadIdx.x;
    int oBase = cTile * BN;
    int cn = counts[f];
    int gBase = bases[f] + lt * BM;       // first gathered row of this tile
    int wRow0 = f * C_OUT + oBase;        // first weight row of this tile

    int wid = tid >> 6;
    int lane = tid & 63;
    int wm = (wid >> 1) * 64;
    int wn = (wid & 1) * 64;
    int lcol = lane & 15;
    int quad = lane >> 4;
    int rp = lcol & 7;                    // read-side swizzle parity

    // staging lane geometry: each wave-issue covers 1 KB = 8 rows x 128 B.
    int lrow = lane >> 3;                 // row within the 8-row segment
    int lchunk = lane & 7;                // 16B chunk within the row
    int schunk = lchunk ^ lrow;           // pre-swizzled SOURCE chunk (T2 via m173)

    const char* aBase = (const char*)gA;
    const char* bBase = (const char*)wb;

    // issue stage 0 first (depends only on SGPR bases), then fill sIdx/sBias;
    // __syncthreads() drains vmcnt(0)+lgkmcnt(0) -> stage 0 complete.
    STAGE(0, 0);
    if (tid < BM) {
        int r = lt * BM + tid;
        sIdx[tid] = (r < cn) ? idxbuf[f * P + r] : -1;
    }
    if (tid < BN) sBias[tid] = bias[f * C_OUT + oBase + tid];
    __syncthreads();

    floatx4 acc[4][4];
#pragma unroll
    for (int i = 0; i < 4; ++i)
#pragma unroll
        for (int j = 0; j < 4; ++j)
            acc[i][j] = (floatx4){0.f, 0.f, 0.f, 0.f};

#pragma unroll
    for (int s = 0; s < C_IN / FBK; ++s) {
        if (s < C_IN / FBK - 1) STAGE(s + 1, (s + 1) & 1);   // prefetch next step

        const ushort* cA = sA[s & 1];
        const ushort* cB = sB[s & 1];
#pragma unroll
        for (int kk2 = 0; kk2 < 2; ++kk2) {
            int ck = ((kk2 * 4 + quad) ^ rp) * 8;   // swizzled 8-elem chunk
            bf16x8 af[4], bfr[4];
#pragma unroll
            for (int i = 0; i < 4; ++i)
                af[i] = *(const bf16x8*)&cA[(wm + i * 16 + lcol) * FBK + ck];
#pragma unroll
            for (int j = 0; j < 4; ++j)
                bfr[j] = *(const bf16x8*)&cB[(wn + j * 16 + lcol) * FBK + ck];
#pragma unroll
            for (int i = 0; i < 4; ++i)
#pragma unroll
                for (int j = 0; j < 4; ++j)
                    acc[i][j] = __builtin_amdgcn_mfma_f32_16x16x32_bf16(af[i], bfr[j], acc[i][j], 0, 0, 0);
        }

        // wait for the prefetched stage, release both buffers to next step.
        // ds_reads above are consumed by MFMAs (lgkmcnt waits precede barrier).
        asm volatile("s_waitcnt vmcnt(0)" ::: "memory");
        __builtin_amdgcn_s_barrier();
        __builtin_amdgcn_sched_barrier(0);
    }

    // epilogue: scatter rows by original point id, add bias
#pragma unroll
    for (int i = 0; i < 4; ++i) {
        int r0 = wm + i * 16 + quad * 4;
        int pid0 = sIdx[r0 + 0];
        int pid1 = sIdx[r0 + 1];
        int pid2 = sIdx[r0 + 2];
        int pid3 = sIdx[r0 + 3];
#pragma unroll
        for (int j = 0; j < 4; ++j) {
            int o = oBase + wn + j * 16 + lcol;
            float bv = sBias[wn + j * 16 + lcol];
            if (pid0 >= 0) out[pid0 * C_OUT + o] = acc[i][j][0] + bv;
            if (pid1 >= 0) out[pid1 * C_OUT + o] = acc[i][j][1] + bv;
            if (pid2 >= 0) out[pid2 * C_OUT + o] = acc[i][j][2] + bv;
            if (pid3 >= 0) out[pid3 * C_OUT + o] = acc[i][j][3] + bv;
        }
    }
}

// ---------------- fallback (old fused) gemm, used only if ws too small ----
__global__ __launch_bounds__(256) void gemm_kernel(
    const float* __restrict__ feat, const ushort* __restrict__ wb,
    const float* __restrict__ bias, const int* __restrict__ idxbuf,
    const int* __restrict__ cnt, float* __restrict__ out, int P)
{
    __shared__ ushort sA[BM * SAS];
    __shared__ ushort sB[BN * SAS];
    __shared__ int    sIdx[BM];
    __shared__ float  sBias[BN];

    int lid = blockIdx.x + (blockIdx.y << 2);
    int g = lid & 7;
    int q = lid >> 3;
    int cTile = q & 3;
    int t = ((q >> 2) << 3) + g;

    int counts[4];
    counts[0] = cnt[0]; counts[1] = cnt[1]; counts[2] = cnt[2]; counts[3] = cnt[3];
    int f = -1, lt = 0;
    for (int ff = 0; ff < 4; ++ff) {
        int nt = (counts[ff] + BM - 1) / BM;
        if (t < nt) { f = ff; lt = t; break; }
        t -= nt;
    }
    if (f < 0) return;

    int tid = threadIdx.x;
    int oBase = cTile * BN;
    int rowBase = lt * BM;
    int cn = counts[f];

    if (tid < BM) {
        int r = rowBase + tid;
        sIdx[tid] = (r < cn) ? idxbuf[f * P + r] : -1;
    }
    if (tid < BN) sBias[tid] = bias[f * C_OUT + oBase + tid];
    __syncthreads();

    int sRow = tid >> 1;
    int sHalf = tid & 1;
    int myIdx = sIdx[sRow];
    const float* aRow = feat + (size_t)(myIdx < 0 ? 0 : myIdx) * C_IN + sHalf * 16;
    const ushort* bRow = wb + (size_t)(f * C_OUT + oBase + sRow) * C_IN + sHalf * 16;

    int wid = tid >> 6;
    int lane = tid & 63;
    int wm = (wid >> 1) * 64;
    int wn = (wid & 1) * 64;
    int lcol = lane & 15;
    int quad = lane >> 4;

    floatx4 acc[4][4];
#pragma unroll
    for (int i = 0; i < 4; ++i)
#pragma unroll
        for (int j = 0; j < 4; ++j)
            acc[i][j] = (floatx4){0.f, 0.f, 0.f, 0.f};

    for (int kk = 0; kk < C_IN; kk += BK) {
        const float* ap = aRow + kk;
        float4 a0 = *(const float4*)(ap + 0);
        float4 a1 = *(const float4*)(ap + 4);
        float4 a2 = *(const float4*)(ap + 8);
        float4 a3 = *(const float4*)(ap + 12);
        const ushort* bp = bRow + kk;
        uint4 b01 = *(const uint4*)(bp + 0);
        uint4 b23 = *(const uint4*)(bp + 8);

        Pack8 p0, p1;
        p0.h[0] = __float2bfloat16(a0.x); p0.h[1] = __float2bfloat16(a0.y);
        p0.h[2] = __float2bfloat16(a0.z); p0.h[3] = __float2bfloat16(a0.w);
        p0.h[4] = __float2bfloat16(a1.x); p0.h[5] = __float2bfloat16(a1.y);
        p0.h[6] = __float2bfloat16(a1.z); p0.h[7] = __float2bfloat16(a1.w);
        p1.h[0] = __float2bfloat16(a2.x); p1.h[1] = __float2bfloat16(a2.y);
        p1.h[2] = __float2bfloat16(a2.z); p1.h[3] = __float2bfloat16(a2.w);
        p1.h[4] = __float2bfloat16(a3.x); p1.h[5] = __float2bfloat16(a3.y);
        p1.h[6] = __float2bfloat16(a3.z); p1.h[7] = __float2bfloat16(a3.w);

        ushort* dA = &sA[sRow * SAS + sHalf * 16];
        *(uint4*)(dA + 0) = p0.u;
        *(uint4*)(dA + 8) = p1.u;
        ushort* dB = &sB[sRow * SAS + sHalf * 16];
        *(uint4*)(dB + 0) = b01;
        *(uint4*)(dB + 8) = b23;

        __syncthreads();

        bf16x8 af[4], bfr[4];
#pragma unroll
        for (int i = 0; i < 4; ++i)
            af[i] = *(const bf16x8*)&sA[(wm + i * 16 + lcol) * SAS + quad * 8];
#pragma unroll
        for (int j = 0; j < 4; ++j)
            bfr[j] = *(const bf16x8*)&sB[(wn + j * 16 + lcol) * SAS + quad * 8];
#pragma unroll
        for (int i = 0; i < 4; ++i)
#pragma unroll
            for (int j = 0; j < 4; ++j)
                acc[i][j] = __builtin_amdgcn_mfma_f32_16x16x32_bf16(af[i], bfr[j], acc[i][j], 0, 0, 0);

        __syncthreads();
    }

#pragma unroll
    for (int i = 0; i < 4; ++i) {
        int r0 = wm + i * 16 + quad * 4;
        int pid0 = sIdx[r0 + 0];
        int pid1 = sIdx[r0 + 1];
        int pid2 = sIdx[r0 + 2];
        int pid3 = sIdx[r0 + 3];
#pragma unroll
        for (int j = 0; j < 4; ++j) {
            int o = oBase + wn + j * 16 + lcol;
            float bv = sBias[wn + j * 16 + lcol];
            if (pid0 >= 0) out[pid0 * C_OUT + o] = acc[i][j][0] + bv;
            if (pid1 >= 0) out[pid1 * C_OUT + o] = acc[i][j][1] + bv;
            if (pid2 >= 0) out[pid2 * C_OUT + o] = acc[i][j][2] + bv;
            if (pid3 >= 0) out[pid3 * C_OUT + o] = acc[i][j][3] + bv;
        }
    }
}

extern "C" void kernel_launch(void* const* d_in, const int* in_sizes, int n_in,
                              void* d_out, int out_size, void* d_ws, size_t ws_size,
                              hipStream_t stream) {
    const float* feat = (const float*)d_in[0];
    const float* xyz  = (const float*)d_in[1];
    const float* w    = (const float*)d_in[2];
    const float* bias = (const float*)d_in[3];
    float* out = (float*)d_out;
    int P = in_sizes[0] / C_IN;

    char* ws = (char*)d_ws;
    size_t offIdx = 0;
    size_t offCnt = (size_t)4 * P * 4;
    size_t offWb  = offCnt + 16;
    size_t offGA  = (offWb + (size_t)NFILT * C_OUT * C_IN * 2 + 255) & ~(size_t)255;
    size_t needed = offGA + (size_t)(P + BM) * C_IN * 2;   // +BM rows slack for padded tiles

    int* idxbuf = (int*)(ws + offIdx);
    int* cntp   = (int*)(ws + offCnt);
    ushort* wb  = (ushort*)(ws + offWb);

    // convert_w also zeroes cnt; stream order guarantees visibility
    convert_w_kernel<<<(NFILT * C_OUT * C_IN) / 1024, 256, 0, stream>>>(w, wb, cntp);
    bucketize_kernel<<<(P + 1023) / 1024, 1024, 0, stream>>>(xyz, idxbuf, cntp, P);

    int tilesY = ((P / BM + NFILT + 7) / 8) * 8;   // padded so XCD swizzle is bijective
    dim3 grid(C_OUT / BN, tilesY);

    if (ws_size >= needed) {
        ushort* gA = (ushort*)(ws + offGA);
        gather_kernel<<<(P + 3) / 4, 256, 0, stream>>>(feat, idxbuf, cntp, gA, P);
        gemm_fast_kernel<<<grid, 256, 0, stream>>>(gA, wb, bias, idxbuf, cntp, out, P);
    } else {
        gemm_kernel<<<grid, 256, 0, stream>>>(feat, wb, bias, idxbuf, cntp, out, P);
    }
}